// Round 5
// baseline (295.103 us; speedup 1.0000x reference)
//
#include <hip/hip_runtime.h>
#include <stdint.h>

using bf16 = __bf16;
typedef __bf16 bf16x8 __attribute__((ext_vector_type(8)));
typedef __bf16 bf16x4 __attribute__((ext_vector_type(4)));
typedef float f32x4 __attribute__((ext_vector_type(4)));

#define H_ 16
#define KV_ 4
#define D_ 128
#define WIN_ 1024
#define B_ 2
#define S_ 2048
#define E_ 2048
#define HD_ 2048

// async global->LDS, 16B per lane. LDS dest must be wave-uniform base + lane*16.
__device__ __forceinline__ void gld_lds16(const void* gptr, void* lptr) {
    __builtin_amdgcn_global_load_lds(
        (__attribute__((address_space(1))) void*)(uintptr_t)gptr,
        (__attribute__((address_space(3))) void*)(uintptr_t)lptr, 16, 0, 0);
}

// ---------------- fused fp32 -> bf16 conversion (x, Wq, Wk, Wv, Wo -> one contiguous dst) ----
__global__ __launch_bounds__(256) void cvt_all(const float* __restrict__ x,
                                               const float* __restrict__ wq,
                                               const float* __restrict__ wk,
                                               const float* __restrict__ wv,
                                               const float* __restrict__ wo,
                                               bf16* __restrict__ dst) {
    int i = (blockIdx.x * 256 + threadIdx.x) * 4;  // into 18,874,368-elem concatenation
    const float* src;
    int off;
    if (i < 8388608)       { src = x;  off = 0; }
    else if (i < 12582912) { src = wq; off = 8388608; }
    else if (i < 13631488) { src = wk; off = 12582912; }
    else if (i < 14680064) { src = wv; off = 13631488; }
    else                   { src = wo; off = 14680064; }
    const float4 v = *(const float4*)(src + (i - off));
    bf16x4 o = {(bf16)v.x, (bf16)v.y, (bf16)v.z, (bf16)v.w};
    *(bf16x4*)(dst + i) = o;
}

// ===================== 2-barrier/K-tile 256-wide GEMM core (unchanged from R4) =========
#define SCHED0() __builtin_amdgcn_sched_barrier(0)
#define BAR()                          \
    do {                               \
        SCHED0();                      \
        __builtin_amdgcn_s_barrier();  \
        SCHED0();                      \
    } while (0)
#define WAITV(N) asm volatile("s_waitcnt vmcnt(" #N ")" ::: "memory")

#define MMA16(MH, NHI, BF)                                                          \
    do {                                                                            \
        __builtin_amdgcn_s_setprio(1);                                              \
        _Pragma("unroll") for (int kh_ = 0; kh_ < 2; ++kh_) {                       \
            _Pragma("unroll") for (int i_ = 0; i_ < 4; ++i_) {                      \
                _Pragma("unroll") for (int j_ = 0; j_ < 2; ++j_) {                  \
                    acc[(MH) * 4 + i_][(NHI) * 2 + j_] =                            \
                        __builtin_amdgcn_mfma_f32_16x16x32_bf16(                    \
                            af[i_][kh_], BF[j_][kh_],                               \
                            acc[(MH) * 4 + i_][(NHI) * 2 + j_], 0, 0, 0);           \
                }                                                                   \
            }                                                                       \
        }                                                                           \
        __builtin_amdgcn_s_setprio(0);                                              \
    } while (0)

// One K-tile, BN=256 (NH=2).
#define TILE_NH2(TT, AC, BC, DOST, WC)                              \
    do {                                                            \
        rdA(AC, 0);                                                 \
        rdB(BC, 0, bf0);                                            \
        rdB(BC, 1, bf1);                                            \
        MMA16(0, 0, bf0);                                           \
        MMA16(0, 1, bf1);                                           \
        rdA(AC, 1);                                                 \
        MMA16(1, 0, bf0);                                           \
        MMA16(1, 1, bf1);                                           \
        BAR();                                                      \
        if (DOST) { stB((TT) + 2, BC); stA((TT) + 2, AC); }         \
        if ((WC) == 8) WAITV(8);                                    \
        else if ((WC) == 0) WAITV(0);                               \
        BAR();                                                      \
    } while (0)

// One K-tile, BN=128 (NH=1).
#define TILE_NH1(TT, AC, BC, DOST, WC)                              \
    do {                                                            \
        rdA(AC, 0);                                                 \
        rdB(BC, 0, bf0);                                            \
        MMA16(0, 0, bf0);                                           \
        rdA(AC, 1);                                                 \
        MMA16(1, 0, bf0);                                           \
        BAR();                                                      \
        if (DOST) { stB((TT) + 2, BC); stA((TT) + 2, AC); }         \
        if ((WC) == 6) WAITV(6);                                    \
        else if ((WC) == 0) WAITV(0);                               \
        BAR();                                                      \
    } while (0)

template <int NH>  // BN = NH*128; NH=2 -> 128KB LDS, NH=1 -> 96KB
__device__ __forceinline__ void gemm_core(const bf16* __restrict__ A,
                                          const bf16* __restrict__ W, int K, int m0,
                                          int n0, bf16* sm, f32x4 (&acc)[8][2 * NH]) {
    const int t = threadIdx.x;
    const int lane = t & 63;
    const int wave = t >> 6;
    const int l15 = lane & 15;
    const int quad = lane >> 4;
    const int fsw8 = (l15 & 7) * 8;
    const int wm = (wave & 1) * 128;           // 2 M-waves x 128 rows
    const int wn = (wave >> 1) * (NH * 32);    // 4 N-waves x NH*32 cols
    const int nt = K >> 6;                     // K-tiles (even, >= 4)

    bf16* const As0 = sm;                      // 256x64 each buffer
    bf16* const As1 = sm + 16384;
    bf16* const Bs0 = sm + 32768;              // NH*128 x 64 each buffer
    bf16* const Bs1 = Bs0 + NH * 8192;

    const int su = ((t & 7) ^ ((t >> 3) & 7)) * 8;  // pre-swizzled source unit
    const bf16* Ap = A + (size_t)(m0 + (t >> 3)) * K + su;
    const bf16* Wp = W + (size_t)(n0 + (t >> 3)) * K + su;

    auto stA = [&](int tt, bf16* dst) {
#pragma unroll
        for (int c = 0; c < 4; ++c)
            gld_lds16(Ap + tt * 64 + (size_t)(c * 64) * K, dst + c * 4096 + t * 8);
    };
    auto stB = [&](int tt, bf16* dst) {
#pragma unroll
        for (int c = 0; c < 2 * NH; ++c)
            gld_lds16(Wp + tt * 64 + (size_t)(c * 64) * K, dst + c * 4096 + t * 8);
    };

    bf16x8 af[4][2], bf0[2][2], bf1[2][2];
    auto rdA = [&](const bf16* S, int mh) {
#pragma unroll
        for (int i = 0; i < 4; ++i) {
            const bf16* r = &S[(wm + mh * 64 + i * 16 + l15) * 64];
#pragma unroll
            for (int kh = 0; kh < 2; ++kh)
                af[i][kh] = *(const bf16x8*)&r[((kh * 4 + quad) * 8) ^ fsw8];
        }
    };
    auto rdB = [&](const bf16* S, int nh, bf16x8 (&f)[2][2]) {
#pragma unroll
        for (int j = 0; j < 2; ++j) {
            const bf16* r = &S[(wn + nh * 32 + j * 16 + l15) * 64];
#pragma unroll
            for (int kh = 0; kh < 2; ++kh)
                f[j][kh] = *(const bf16x8*)&r[((kh * 4 + quad) * 8) ^ fsw8];
        }
    };

    // prologue: stage tiles 0 and 1; retire tile 0 own-wave (tile 1 stays in flight);
    // barrier makes tile 0 globally visible before any wave reads it.
    stA(0, As0);
    stB(0, Bs0);
    stA(1, As1);
    stB(1, Bs1);
    SCHED0();
    if constexpr (NH == 2) WAITV(8);
    else WAITV(6);
    BAR();

    if constexpr (NH == 2) {
        for (int tt = 0; tt < nt - 2; tt += 2) {
            TILE_NH2(tt, As0, Bs0, 1, 8);
            TILE_NH2(tt + 1, As1, Bs1, 1, 8);
        }
        TILE_NH2(nt - 2, As0, Bs0, 0, 0);
        TILE_NH2(nt - 1, As1, Bs1, 0, -1);
    } else {
        for (int tt = 0; tt < nt - 2; tt += 2) {
            TILE_NH1(tt, As0, Bs0, 1, 6);
            TILE_NH1(tt + 1, As1, Bs1, 1, 6);
        }
        TILE_NH1(nt - 2, As0, Bs0, 0, 0);
        TILE_NH1(nt - 1, As1, Bs1, 0, -1);
    }
}

// ---------------- QKV GEMM (256x256 tiles) with fused RoPE + RMSNorm + V-transpose ----
__global__ __launch_bounds__(512, 2) void gemm_qkv8(const bf16* __restrict__ A,
                                                    const bf16* __restrict__ W,
                                                    const float* __restrict__ cosp,
                                                    const float* __restrict__ sinp,
                                                    bf16* __restrict__ qn,
                                                    bf16* __restrict__ kn,
                                                    bf16* __restrict__ vt) {
    __shared__ alignas(16) bf16 sm[65536];  // 128 KB (K-loop); epilogue chunk aliases it
    const int flat = blockIdx.y * 16 + blockIdx.x;  // nwg=192, 192%8==0 -> bijective
    const int swz = (flat & 7) * 24 + (flat >> 3);  // XCD-contiguous tile chunks
    const int m0 = (swz & 15) * 256;
    const int n0 = (swz >> 4) * 256;

    f32x4 acc[8][4] = {};
    gemm_core<2>(A, W, E_, m0, n0, sm, acc);

    const int t = threadIdx.x;
    const int lane = t & 63;
    const int wave = t >> 6;
    const int l15 = lane & 15;
    const int quad = lane >> 4;
    const int wm = (wave & 1) * 128;
    const int wn = (wave >> 1) * 64;
    bf16* Cs = sm;  // [128][264] per chunk; 264*2B row stride = 33x16B (aligned, 4-way max)

#pragma unroll
    for (int ch = 0; ch < 2; ++ch) {
        __syncthreads();
        if (wm == ch * 128) {  // half the waves own this 128-row chunk
#pragma unroll
            for (int mi = 0; mi < 8; ++mi) {
                const int rl = mi * 16 + quad * 4;
#pragma unroll
                for (int nf = 0; nf < 4; ++nf) {
                    const int col = wn + nf * 16 + l15;
#pragma unroll
                    for (int r = 0; r < 4; ++r)
                        Cs[(rl + r) * 264 + col] = (bf16)acc[mi][nf][r];
                }
            }
        }
        __syncthreads();

        if (n0 < 2560) {
            // q/k tile: 2 threads per (token-row, head); each handles d = half*32..+31
            const int rt = t >> 1;       // 0..255
            const int row = rt & 127;
            const int hh = rt >> 7;      // which of the 2 heads in this tile
            const int half = t & 1;
            const int gr = m0 + ch * 128 + row;
            const int bb = gr >> 11;
            const int s = gr & 2047;
            const int unit = (n0 >> 7) + hh;
            const bf16* crow = &Cs[row * 264 + hh * 128 + half * 32];
            const float* cp = cosp + s * 64 + half * 32;
            const float* sp = sinp + s * 64 + half * 32;
            bf16x8 xa[4], xb2[4];
#pragma unroll
            for (int u = 0; u < 4; ++u) {
                xa[u] = *(const bf16x8*)(crow + u * 8);
                xb2[u] = *(const bf16x8*)(crow + 64 + u * 8);
            }
            float y1[32], y2[32], ss = 0.0f;
#pragma unroll
            for (int u = 0; u < 4; ++u)
#pragma unroll
                for (int e = 0; e < 8; ++e) {
                    const int jj = u * 8 + e;
                    const float x1 = (float)xa[u][e];
                    const float x2 = (float)xb2[u][e];
                    const float c = cp[jj];
                    const float sn = sp[jj];
                    y1[jj] = x1 * c + x2 * sn;
                    y2[jj] = x2 * c - x1 * sn;
                    ss += y1[jj] * y1[jj] + y2[jj] * y2[jj];
                }
            ss += __shfl_xor(ss, 1, 64);
            float rr = rsqrtf(ss * (1.0f / 128.0f) + 1.1920929e-7f);
            bf16* dst;
            if (unit < 16) {
                rr *= 0.12751740f;  // D^-0.5 * log2(e): exp2-domain softmax in attn
                dst = qn + ((size_t)(bb * H_ + unit) * S_ + s) * 128 + half * 32;
            } else {
                dst = kn + ((size_t)(bb * KV_ + (unit - 16)) * S_ + s) * 128 + half * 32;
            }
#pragma unroll
            for (int u = 0; u < 4; ++u) {
                bf16x8 p1, p2;
#pragma unroll
                for (int e = 0; e < 8; ++e) {
                    p1[e] = (bf16)(y1[u * 8 + e] * rr);
                    p2[e] = (bf16)(y2[u * 8 + e] * rr);
                }
                *(bf16x8*)(dst + u * 8) = p1;
                *(bf16x8*)(dst + 64 + u * 8) = p2;
            }
        } else {
            // V tile: transpose chunk -> vt[(b,jv,d,s)]; thread owns one (head,d), 64 s
            const int hh = t >> 8;
            const int d = (t >> 1) & 127;
            const int sl0 = (t & 1) * 64;
            const int jv = (n0 >> 7) + hh - 20;
            const int base = m0 + ch * 128;
            const int bb = base >> 11;
            const int sW = (base & 2047) + sl0;
            bf16* vdst = vt + ((size_t)(bb * KV_ + jv) * 128 + d) * S_ + sW;
#pragma unroll
            for (int u = 0; u < 8; ++u) {
                bf16x8 pk;
#pragma unroll
                for (int e = 0; e < 8; ++e)
                    pk[e] = Cs[(sl0 + u * 8 + e) * 264 + hh * 128 + d];
                *(bf16x8*)(vdst + u * 8) = pk;
            }
        }
    }
}

// ---------------- out-projection: C[m,n] = sum_k A[m,k] * W[n,k], 256x128 tiles -------
__global__ __launch_bounds__(512, 2) void gemm_bt8(const bf16* __restrict__ A,
                                                   const bf16* __restrict__ W,
                                                   float* __restrict__ C, int K,
                                                   int ldc) {
    __shared__ alignas(16) bf16 sm[49152];  // 96 KB
    const int flat = blockIdx.y * 16 + blockIdx.x;  // nwg=256
    const int swz = (flat & 7) * 32 + (flat >> 3);
    const int m0 = (swz & 15) * 256;
    const int n0 = (swz >> 4) * 128;

    f32x4 acc[8][2] = {};
    gemm_core<1>(A, W, K, m0, n0, sm, acc);

    const int t = threadIdx.x;
    const int lane = t & 63;
    const int l15 = lane & 15;
    const int quad = lane >> 4;
    const int wave = t >> 6;
    const int wm = (wave & 1) * 128;
    const int wn = (wave >> 1) * 32;
#pragma unroll
    for (int mi = 0; mi < 8; ++mi) {
        const int row = m0 + wm + mi * 16 + quad * 4;
#pragma unroll
        for (int j = 0; j < 2; ++j) {
            const int col = n0 + wn + j * 16 + l15;
#pragma unroll
            for (int r = 0; r < 4; ++r) C[(size_t)(row + r) * ldc + col] = acc[mi][j][r];
        }
    }
}

// ---------------- flash attention, sliding window, S^T orientation --------------------
// v2: double-buffered K/V staging (T3 2-phase: issue next tile's global_load_lds BEFORE
// compute, drain vmcnt(0)+syncthreads only at tile end -> stage overlaps QK^T/softmax/PV)
// + setprio(1) around MFMA clusters (T5; attn blocks are independent, scheduler can
// arbitrate). LDS 72 KB -> 2 blocks/CU (was 4): overlap replaces TLP.
// Hazards: stages into buf c^1 issue after the barrier that retired all waves' reads of
// c^1 (MFMA register consumption forces lgkm retirement pre-barrier); reads of buf c are
// protected by prev iteration's vmcnt(0)+__syncthreads (IR-level memory fence: no hoist).
__global__ __launch_bounds__(256, 2) void attn_fwd(const bf16* __restrict__ Qn,
                                                   const bf16* __restrict__ Kn,
                                                   const bf16* __restrict__ Vt,
                                                   bf16* __restrict__ Out) {
    __shared__ alignas(16) bf16 Ks[2][64 * 128];
    __shared__ alignas(16) bf16 Vs[2][128 * 64];
    __shared__ alignas(16) bf16 Ps[4 * 16 * 64];

    const int t = threadIdx.x;
    const int lane = t & 63;
    const int wave = t >> 6;
    const int l15 = lane & 15;
    const int quad = lane >> 4;
    const int swz = l15 & 7;
    const int qb0 = blockIdx.x * 64;
    const int h = blockIdx.y;
    const int b = blockIdx.z;
    const int hk = h >> 2;
    const int qw0 = qb0 + wave * 16;

    const bf16* qbase = Qn + ((size_t)((b * H_ + h) * S_) + qw0 + l15) * 128;
    bf16x8 qf[4];
#pragma unroll
    for (int c4 = 0; c4 < 4; ++c4) qf[c4] = *(const bf16x8*)(qbase + c4 * 32 + quad * 8);

    f32x4 o[8] = {};
    float m = -1e30f, lsum = 0.0f;

    const bf16* kroot = Kn + (size_t)((b * KV_ + hk) * S_) * 128;
    const bf16* vroot = Vt + (size_t)((b * KV_ + hk) * 128) * S_;

    const int ku = (t & 15) ^ ((t >> 4) & 7);
    const int krow = t >> 4;
    const int vu = (t & 7) ^ ((t >> 3) & 7);
    const int vrow = t >> 3;
    const bf16* kst = kroot + (size_t)krow * 128 + ku * 8;
    const bf16* vst = vroot + (size_t)vrow * S_ + vu * 8;

    auto stage = [&](int kb, int c) {
        bf16* ksl = &Ks[c][t * 8];
        bf16* vsl = &Vs[c][t * 8];
#pragma unroll
        for (int cc = 0; cc < 4; ++cc)
            gld_lds16(kst + (size_t)(kb + cc * 16) * 128, ksl + cc * 2048);
#pragma unroll
        for (int cc = 0; cc < 4; ++cc)
            gld_lds16(vst + (size_t)(cc * 32) * S_ + kb, vsl + cc * 2048);
    };

    int lo = qb0 - (WIN_ - 1);
    if (lo < 0) lo = 0;
    const int kb_start = lo & ~63;
    const int kb_end = qb0 + 64;

    // prologue: stage first tile into buffer 0, drain, sync
    stage(kb_start, 0);
    WAITV(0);
    __syncthreads();

    int cur = 0;
    for (int kb = kb_start; kb < kb_end; kb += 64) {
        // issue next tile's staging early -> lands during this tile's compute
        if (kb + 64 < kb_end) stage(kb + 64, cur ^ 1);

        const bool wave_active = (kb + 63 >= qw0 - (WIN_ - 1));
        if (wave_active) {
            const bf16* Kc = &Ks[cur][0];
            const bf16* Vc = &Vs[cur][0];
            f32x4 sacc[4] = {};
            __builtin_amdgcn_s_setprio(1);
#pragma unroll
            for (int c4 = 0; c4 < 4; ++c4)
#pragma unroll
                for (int kblk = 0; kblk < 4; ++kblk) {
                    bf16x8 kf = *(const bf16x8*)&Kc[(kblk * 16 + l15) * 128 +
                                                    (((c4 * 4 + quad) ^ swz) * 8)];
                    sacc[kblk] =
                        __builtin_amdgcn_mfma_f32_16x16x32_bf16(kf, qf[c4], sacc[kblk], 0, 0, 0);
                }
            __builtin_amdgcn_s_setprio(0);

            const int q = qw0 + l15;
            float sv[16];
            const bool interior = (kb + 63 <= qw0) && (kb >= qw0 + 15 - (WIN_ - 1));
            if (interior) {
#pragma unroll
                for (int kblk = 0; kblk < 4; ++kblk)
#pragma unroll
                    for (int r = 0; r < 4; ++r) sv[kblk * 4 + r] = sacc[kblk][r];
            } else {
#pragma unroll
                for (int kblk = 0; kblk < 4; ++kblk)
#pragma unroll
                    for (int r = 0; r < 4; ++r) {
                        const int key = kb + kblk * 16 + quad * 4 + r;
                        const bool valid = (key <= q) && (q - key < WIN_);
                        sv[kblk * 4 + r] = valid ? sacc[kblk][r] : -1e30f;
                    }
            }
            float mc = sv[0];
#pragma unroll
            for (int i = 1; i < 16; ++i) mc = fmaxf(mc, sv[i]);
            mc = fmaxf(mc, __shfl_xor(mc, 16, 64));
            mc = fmaxf(mc, __shfl_xor(mc, 32, 64));
            const float mnew = fmaxf(m, mc);
            const float al = __builtin_amdgcn_exp2f(m - mnew);
            float ls = 0.0f;
#pragma unroll
            for (int i = 0; i < 16; ++i) {
                sv[i] = __builtin_amdgcn_exp2f(sv[i] - mnew);
                ls += sv[i];
            }
            ls += __shfl_xor(ls, 16, 64);
            ls += __shfl_xor(ls, 32, 64);
            lsum = lsum * al + ls;
            m = mnew;
#pragma unroll
            for (int dblk = 0; dblk < 8; ++dblk) o[dblk] *= al;

            bf16* pw = &Ps[wave * 1024 + l15 * 64];
#pragma unroll
            for (int kblk = 0; kblk < 4; ++kblk) {
                bf16x4 pb = {(bf16)sv[kblk * 4 + 0], (bf16)sv[kblk * 4 + 1],
                             (bf16)sv[kblk * 4 + 2], (bf16)sv[kblk * 4 + 3]};
                const int phys = (kblk * 2 + (quad >> 1)) ^ swz;
                *(bf16x4*)&pw[phys * 8 + (quad & 1) * 4] = pb;
            }
            __builtin_amdgcn_s_setprio(1);
#pragma unroll
            for (int kc = 0; kc < 2; ++kc) {
                const int up = ((kc * 4 + quad) ^ swz) * 8;
                bf16x8 pfv = *(const bf16x8*)&pw[up];
#pragma unroll
                for (int dblk = 0; dblk < 8; ++dblk) {
                    bf16x8 vf = *(const bf16x8*)&Vc[(dblk * 16 + l15) * 64 + up];
                    o[dblk] = __builtin_amdgcn_mfma_f32_16x16x32_bf16(vf, pfv, o[dblk], 0, 0, 0);
                }
            }
            __builtin_amdgcn_s_setprio(0);
        }
        // drain next tile's staging (overlapped with the compute above), then sync
        WAITV(0);
        __syncthreads();
        cur ^= 1;
    }

    const float inv = 1.0f / lsum;
    const int q = qw0 + l15;
    bf16* ob = Out + (size_t)(b * S_ + q) * HD_ + h * 128;
#pragma unroll
    for (int dblk = 0; dblk < 8; ++dblk) {
        bf16x4 ov = {(bf16)(o[dblk][0] * inv), (bf16)(o[dblk][1] * inv),
                     (bf16)(o[dblk][2] * inv), (bf16)(o[dblk][3] * inv)};
        *(bf16x4*)&ob[dblk * 16 + quad * 4] = ov;
    }
}

// ---------------- launch ----------------
extern "C" void kernel_launch(void* const* d_in, const int* in_sizes, int n_in, void* d_out,
                              int out_size, void* d_ws, size_t ws_size, hipStream_t stream) {
    const float* x = (const float*)d_in[0];
    const float* cosp = (const float*)d_in[1];
    const float* sinp = (const float*)d_in[2];
    const float* Wq = (const float*)d_in[3];
    const float* Wk = (const float*)d_in[4];
    const float* Wv = (const float*)d_in[5];
    const float* Wo = (const float*)d_in[6];
    float* out = (float*)d_out;

    constexpr size_t MB = 1ull << 20;
    char* ws = (char*)d_ws;
    bf16* xb    = (bf16*)(ws + 0);          // x bf16 (4096x2048)        16 MB
    bf16* wqkv  = (bf16*)(ws + 16 * MB);    // Wq|Wk|Wv bf16 (3072x2048) 12 MB
    bf16* wo    = (bf16*)(ws + 28 * MB);    // Wo bf16 (2048x2048)        8 MB
    bf16* qn    = (bf16*)(ws + 40 * MB);    // (B,H,S,D)                 16 MB
    bf16* kn    = (bf16*)(ws + 56 * MB);    // (B,KV,S,D)                 4 MB
    bf16* vt    = (bf16*)(ws + 60 * MB);    // (B,KV,D,S)                 4 MB
    bf16* attnb = (bf16*)(ws + 64 * MB);    // (B,S,H*D)                 16 MB

    cvt_all<<<18432, 256, 0, stream>>>(x, Wq, Wk, Wv, Wo, xb);
    gemm_qkv8<<<dim3(16, 12), 512, 0, stream>>>(xb, wqkv, cosp, sinp, qn, kn, vt);
    attn_fwd<<<dim3(32, 16, 2), 256, 0, stream>>>(qn, kn, vt, attnb);
    gemm_bt8<<<dim3(16, 16), 512, 0, stream>>>(attnb, wo, out, 2048, 2048);
}

// Round 6
// 277.720 us; speedup vs baseline: 1.0626x; 1.0626x over previous
//
#include <hip/hip_runtime.h>
#include <stdint.h>

using bf16 = __bf16;
typedef __bf16 bf16x8 __attribute__((ext_vector_type(8)));
typedef __bf16 bf16x4 __attribute__((ext_vector_type(4)));
typedef float f32x4 __attribute__((ext_vector_type(4)));

#define H_ 16
#define KV_ 4
#define D_ 128
#define WIN_ 1024
#define B_ 2
#define S_ 2048
#define E_ 2048
#define HD_ 2048

// async global->LDS, 16B per lane. LDS dest must be wave-uniform base + lane*16.
__device__ __forceinline__ void gld_lds16(const void* gptr, void* lptr) {
    __builtin_amdgcn_global_load_lds(
        (__attribute__((address_space(1))) void*)(uintptr_t)gptr,
        (__attribute__((address_space(3))) void*)(uintptr_t)lptr, 16, 0, 0);
}

// ---------------- fused fp32 -> bf16 conversion (x, Wq, Wk, Wv, Wo -> one contiguous dst) ----
__global__ __launch_bounds__(256) void cvt_all(const float* __restrict__ x,
                                               const float* __restrict__ wq,
                                               const float* __restrict__ wk,
                                               const float* __restrict__ wv,
                                               const float* __restrict__ wo,
                                               bf16* __restrict__ dst) {
    int i = (blockIdx.x * 256 + threadIdx.x) * 4;  // into 18,874,368-elem concatenation
    const float* src;
    int off;
    if (i < 8388608)       { src = x;  off = 0; }
    else if (i < 12582912) { src = wq; off = 8388608; }
    else if (i < 13631488) { src = wk; off = 12582912; }
    else if (i < 14680064) { src = wv; off = 13631488; }
    else                   { src = wo; off = 14680064; }
    const float4 v = *(const float4*)(src + (i - off));
    bf16x4 o = {(bf16)v.x, (bf16)v.y, (bf16)v.z, (bf16)v.w};
    *(bf16x4*)(dst + i) = o;
}

#define SCHED0() __builtin_amdgcn_sched_barrier(0)
#define BAR()                          \
    do {                               \
        SCHED0();                      \
        __builtin_amdgcn_s_barrier();  \
        SCHED0();                      \
    } while (0)
#define WAITV(N) asm volatile("s_waitcnt vmcnt(" #N ")" ::: "memory")

// ===================== BK=32, 4-deep pipelined, register-double-buffered GEMM core ====
// LDS layout: row = 32 bf16 = 64 B (half bank wrap) -> fragment reads (row=...+l15,
// 16B at quad*16) and linear staging are naturally conflict-free; NO swizzle.
// 4 LDS buffers per operand. Tile u:
//   stage(u+3) issued first (VMEM latency budget = 3 tiles);
//   MFMA tile u from REGISTERS (frags read during tile u-1 -> zero lgkm on the
//   critical path); 32 MFMA (NH=2), all-independent accumulators;
//   ds_read tile u+1's fragments into the spare register set (hidden under MFMA;
//   buf(u+1) is globally valid: stage(u+1) retired by end-of-(u-1) WAITV + barrier);
//   WAITV(4|3): retires stage(u+2) for next tile's reads, keeps stage(u+3) in flight
//   (never 0 in steady state); one barrier per tile.
// WAR safety: stage into buf(u+3)%4 = buf(u-1)%4, whose last reads (during tile u-2)
// were lgkm-drained by their consuming MFMAs during tile u-1, before BAR(end u-1) ->
// stage at tile u start is >= one full barrier later. Fully barrier-ordered.

template <int NH>  // BN = NH*128; NH=2 -> 128KB LDS, NH=1 -> 96KB
__device__ __forceinline__ void gemm_core32(const bf16* __restrict__ A,
                                            const bf16* __restrict__ W, int m0,
                                            int n0, bf16* sm, f32x4 (&acc)[8][2 * NH]) {
    constexpr int K = 2048;  // both GEMMs have K=2048; 64 K-tiles of 32
    const int t = threadIdx.x;
    const int lane = t & 63;
    const int wave = t >> 6;
    const int l15 = lane & 15;
    const int quad = lane >> 4;
    const int wm = (wave & 1) * 128;         // 2 M-waves x 128 rows
    const int wn = (wave >> 1) * (NH * 32);  // 4 N-waves x NH*32 cols

    bf16* const A0 = sm;                     // 4 A-buffers, 256x32 = 8192 elems each
    bf16* const A1 = sm + 8192;
    bf16* const A2 = sm + 16384;
    bf16* const A3 = sm + 24576;
    bf16* const B0 = sm + 32768;             // 4 B-buffers, NH*128 x 32 each
    bf16* const B1 = B0 + NH * 4096;
    bf16* const B2 = B0 + NH * 8192;
    bf16* const B3 = B0 + NH * 12288;

    // staging: thread t -> row (t>>2) [+128 for round 1], 16B unit (t&3); linear LDS
    const bf16* Ap = A + (size_t)(m0 + (t >> 2)) * K + (t & 3) * 8;
    const bf16* Wp = W + (size_t)(n0 + (t >> 2)) * K + (t & 3) * 8;

    auto stA = [&](int u, bf16* d) {
        gld_lds16(Ap + u * 32, d + t * 8);
        gld_lds16(Ap + u * 32 + (size_t)128 * K, d + 4096 + t * 8);
    };
    auto stB = [&](int u, bf16* d) {
        gld_lds16(Wp + u * 32, d + t * 8);
        if constexpr (NH == 2) gld_lds16(Wp + u * 32 + (size_t)128 * K, d + 4096 + t * 8);
    };

    bf16x8 afX[8], afY[8], bfX[2 * NH], bfY[2 * NH];
    auto rdA = [&](const bf16* S, bf16x8 (&af)[8]) {
#pragma unroll
        for (int mi = 0; mi < 8; ++mi)
            af[mi] = *(const bf16x8*)&S[(wm + mi * 16 + l15) * 32 + quad * 8];
    };
    auto rdB = [&](const bf16* S, bf16x8 (&bf)[2 * NH]) {
#pragma unroll
        for (int j = 0; j < 2 * NH; ++j)
            bf[j] = *(const bf16x8*)&S[(wn + j * 16 + l15) * 32 + quad * 8];
    };
    auto MMA = [&](bf16x8 (&af)[8], bf16x8 (&bf)[2 * NH]) {
        __builtin_amdgcn_s_setprio(1);
#pragma unroll
        for (int mi = 0; mi < 8; ++mi)
#pragma unroll
            for (int j = 0; j < 2 * NH; ++j)
                acc[mi][j] = __builtin_amdgcn_mfma_f32_16x16x32_bf16(af[mi], bf[j],
                                                                     acc[mi][j], 0, 0, 0);
        __builtin_amdgcn_s_setprio(0);
    };

#define GT(U, AFM, BFM, AFR, BFR, RA, RB, SA, SB, DOST, WMODE)                      \
    do {                                                                            \
        if (DOST) { stA((U) + 3, SA); stB((U) + 3, SB); }                           \
        MMA(AFM, BFM);                                                              \
        rdA(RA, AFR);                                                               \
        rdB(RB, BFR);                                                               \
        SCHED0();                                                                   \
        if ((WMODE) == 1) {                                                         \
            if constexpr (NH == 2) { WAITV(4); } else { WAITV(3); }                 \
        } else if ((WMODE) == 0) {                                                  \
            WAITV(0);                                                               \
        }                                                                           \
        BAR();                                                                      \
    } while (0)

    // prologue: stage tiles 0,1,2; retire 0 and 1 (2 stays in flight); read frag 0.
    stA(0, A0); stB(0, B0);
    stA(1, A1); stB(1, B1);
    stA(2, A2); stB(2, B2);
    SCHED0();
    if constexpr (NH == 2) { WAITV(4); } else { WAITV(3); }
    BAR();
    rdA(A0, afX);
    rdB(B0, bfX);

    // tiles 0..59: 15 iterations x 4 (buffer cycle and X/Y parity both period-4)
    for (int it = 0; it < 15; ++it) {
        const int u = it * 4;
        GT(u + 0, afX, bfX, afY, bfY, A1, B1, A3, B3, 1, 1);
        GT(u + 1, afY, bfY, afX, bfX, A2, B2, A0, B0, 1, 1);
        GT(u + 2, afX, bfX, afY, bfY, A3, B3, A1, B1, 1, 1);
        GT(u + 3, afY, bfY, afX, bfX, A0, B0, A2, B2, 1, 1);
    }
    GT(60, afX, bfX, afY, bfY, A1, B1, A3, B3, 1, 1);   // stages tile 63 -> b3
    GT(61, afY, bfY, afX, bfX, A2, B2, A0, B0, 0, 0);   // drain: stage(63) retired
    GT(62, afX, bfX, afY, bfY, A3, B3, A1, B1, 0, -1);  // reads frag 63 from b3
    MMA(afY, bfY);                                      // tile 63
#undef GT
}

// ---------------- QKV GEMM (256x256 tiles) with fused RoPE + RMSNorm + V-transpose ----
// grid = 16 M-tiles x 12 N-tiles. Each 256-col tile = exactly 2 heads of one kind:
// by 0..7 = q heads (units 0..15), by 8..9 = k (16..19), by 10..11 = v (20..23).
// Epilogue processes the tile in two 128-row chunks through a [128][264] LDS stash.
__global__ __launch_bounds__(512, 2) void gemm_qkv8(const bf16* __restrict__ A,
                                                    const bf16* __restrict__ W,
                                                    const float* __restrict__ cosp,
                                                    const float* __restrict__ sinp,
                                                    bf16* __restrict__ qn,
                                                    bf16* __restrict__ kn,
                                                    bf16* __restrict__ vt) {
    __shared__ alignas(16) bf16 sm[65536];  // 128 KB (K-loop); epilogue chunk aliases it
    const int flat = blockIdx.y * 16 + blockIdx.x;  // nwg=192, 192%8==0 -> bijective
    const int swz = (flat & 7) * 24 + (flat >> 3);  // XCD-contiguous tile chunks
    const int m0 = (swz & 15) * 256;
    const int n0 = (swz >> 4) * 256;

    f32x4 acc[8][4] = {};
    gemm_core32<2>(A, W, m0, n0, sm, acc);

    const int t = threadIdx.x;
    const int lane = t & 63;
    const int wave = t >> 6;
    const int l15 = lane & 15;
    const int quad = lane >> 4;
    const int wm = (wave & 1) * 128;
    const int wn = (wave >> 1) * 64;
    bf16* Cs = sm;  // [128][264] per chunk; 264*2B row stride = 33x16B (aligned, 4-way max)

#pragma unroll
    for (int ch = 0; ch < 2; ++ch) {
        __syncthreads();
        if (wm == ch * 128) {  // half the waves own this 128-row chunk
#pragma unroll
            for (int mi = 0; mi < 8; ++mi) {
                const int rl = mi * 16 + quad * 4;
#pragma unroll
                for (int nf = 0; nf < 4; ++nf) {
                    const int col = wn + nf * 16 + l15;
#pragma unroll
                    for (int r = 0; r < 4; ++r)
                        Cs[(rl + r) * 264 + col] = (bf16)acc[mi][nf][r];
                }
            }
        }
        __syncthreads();

        if (n0 < 2560) {
            // q/k tile: 2 threads per (token-row, head); each handles d = half*32..+31
            const int rt = t >> 1;       // 0..255
            const int row = rt & 127;
            const int hh = rt >> 7;      // which of the 2 heads in this tile
            const int half = t & 1;
            const int gr = m0 + ch * 128 + row;
            const int bb = gr >> 11;
            const int s = gr & 2047;
            const int unit = (n0 >> 7) + hh;
            const bf16* crow = &Cs[row * 264 + hh * 128 + half * 32];
            const float* cp = cosp + s * 64 + half * 32;
            const float* sp = sinp + s * 64 + half * 32;
            bf16x8 xa[4], xb2[4];
#pragma unroll
            for (int u = 0; u < 4; ++u) {
                xa[u] = *(const bf16x8*)(crow + u * 8);
                xb2[u] = *(const bf16x8*)(crow + 64 + u * 8);
            }
            float y1[32], y2[32], ss = 0.0f;
#pragma unroll
            for (int u = 0; u < 4; ++u)
#pragma unroll
                for (int e = 0; e < 8; ++e) {
                    const int jj = u * 8 + e;
                    const float x1 = (float)xa[u][e];
                    const float x2 = (float)xb2[u][e];
                    const float c = cp[jj];
                    const float sn = sp[jj];
                    y1[jj] = x1 * c + x2 * sn;
                    y2[jj] = x2 * c - x1 * sn;
                    ss += y1[jj] * y1[jj] + y2[jj] * y2[jj];
                }
            ss += __shfl_xor(ss, 1, 64);
            float rr = rsqrtf(ss * (1.0f / 128.0f) + 1.1920929e-7f);
            bf16* dst;
            if (unit < 16) {
                rr *= 0.12751740f;  // D^-0.5 * log2(e): exp2-domain softmax in attn
                dst = qn + ((size_t)(bb * H_ + unit) * S_ + s) * 128 + half * 32;
            } else {
                dst = kn + ((size_t)(bb * KV_ + (unit - 16)) * S_ + s) * 128 + half * 32;
            }
#pragma unroll
            for (int u = 0; u < 4; ++u) {
                bf16x8 p1, p2;
#pragma unroll
                for (int e = 0; e < 8; ++e) {
                    p1[e] = (bf16)(y1[u * 8 + e] * rr);
                    p2[e] = (bf16)(y2[u * 8 + e] * rr);
                }
                *(bf16x8*)(dst + u * 8) = p1;
                *(bf16x8*)(dst + 64 + u * 8) = p2;
            }
        } else {
            // V tile: transpose chunk -> vt[(b,jv,d,s)]; thread owns one (head,d), 64 s
            const int hh = t >> 8;
            const int d = (t >> 1) & 127;
            const int sl0 = (t & 1) * 64;
            const int jv = (n0 >> 7) + hh - 20;
            const int base = m0 + ch * 128;
            const int bb = base >> 11;
            const int sW = (base & 2047) + sl0;
            bf16* vdst = vt + ((size_t)(bb * KV_ + jv) * 128 + d) * S_ + sW;
#pragma unroll
            for (int u = 0; u < 8; ++u) {
                bf16x8 pk;
#pragma unroll
                for (int e = 0; e < 8; ++e)
                    pk[e] = Cs[(sl0 + u * 8 + e) * 264 + hh * 128 + d];
                *(bf16x8*)(vdst + u * 8) = pk;
            }
        }
    }
}

// ---------------- out-projection: C[m,n] = sum_k A[m,k] * W[n,k], 256x128 tiles -------
__global__ __launch_bounds__(512, 2) void gemm_bt8(const bf16* __restrict__ A,
                                                   const bf16* __restrict__ W,
                                                   float* __restrict__ C, int K,
                                                   int ldc) {
    __shared__ alignas(16) bf16 sm[49152];  // 96 KB
    const int flat = blockIdx.y * 16 + blockIdx.x;  // nwg=256
    const int swz = (flat & 7) * 32 + (flat >> 3);
    const int m0 = (swz & 15) * 256;
    const int n0 = (swz >> 4) * 128;

    f32x4 acc[8][2] = {};
    gemm_core32<1>(A, W, m0, n0, sm, acc);

    const int t = threadIdx.x;
    const int lane = t & 63;
    const int l15 = lane & 15;
    const int quad = lane >> 4;
    const int wave = t >> 6;
    const int wm = (wave & 1) * 128;
    const int wn = (wave >> 1) * 32;
#pragma unroll
    for (int mi = 0; mi < 8; ++mi) {
        const int row = m0 + wm + mi * 16 + quad * 4;
#pragma unroll
        for (int j = 0; j < 2; ++j) {
            const int col = n0 + wn + j * 16 + l15;
#pragma unroll
            for (int r = 0; r < 4; ++r) C[(size_t)(row + r) * ldc + col] = acc[mi][j][r];
        }
    }
}

// ---------------- flash attention, sliding window, S^T orientation (R4 version) -------
// QK^T loop: c4 OUTER so consecutive MFMAs hit different sacc[kblk] (dep distance 4).
__global__ __launch_bounds__(256, 4) void attn_fwd(const bf16* __restrict__ Qn,
                                                   const bf16* __restrict__ Kn,
                                                   const bf16* __restrict__ Vt,
                                                   bf16* __restrict__ Out) {
    __shared__ alignas(16) bf16 Ks[64 * 128];
    __shared__ alignas(16) bf16 Vs[128 * 64];
    __shared__ alignas(16) bf16 Ps[4 * 16 * 64];

    const int t = threadIdx.x;
    const int lane = t & 63;
    const int wave = t >> 6;
    const int l15 = lane & 15;
    const int quad = lane >> 4;
    const int swz = l15 & 7;
    const int qb0 = blockIdx.x * 64;
    const int h = blockIdx.y;
    const int b = blockIdx.z;
    const int hk = h >> 2;
    const int qw0 = qb0 + wave * 16;

    const bf16* qbase = Qn + ((size_t)((b * H_ + h) * S_) + qw0 + l15) * 128;
    bf16x8 qf[4];
#pragma unroll
    for (int c4 = 0; c4 < 4; ++c4) qf[c4] = *(const bf16x8*)(qbase + c4 * 32 + quad * 8);

    f32x4 o[8] = {};
    float m = -1e30f, lsum = 0.0f;

    const bf16* kroot = Kn + (size_t)((b * KV_ + hk) * S_) * 128;
    const bf16* vroot = Vt + (size_t)((b * KV_ + hk) * 128) * S_;

    const int ku = (t & 15) ^ ((t >> 4) & 7);
    const int krow = t >> 4;
    const int vu = (t & 7) ^ ((t >> 3) & 7);
    const int vrow = t >> 3;
    const bf16* kst = kroot + (size_t)krow * 128 + ku * 8;
    const bf16* vst = vroot + (size_t)vrow * S_ + vu * 8;
    bf16* ksl = &Ks[t * 8];
    bf16* vsl = &Vs[t * 8];

    int lo = qb0 - (WIN_ - 1);
    if (lo < 0) lo = 0;
    const int kb_start = lo & ~63;
    const int kb_end = qb0 + 64;

    for (int kb = kb_start; kb < kb_end; kb += 64) {
#pragma unroll
        for (int c = 0; c < 4; ++c) gld_lds16(kst + (size_t)(kb + c * 16) * 128, ksl + c * 2048);
#pragma unroll
        for (int c = 0; c < 4; ++c) gld_lds16(vst + (size_t)(c * 32) * S_ + kb, vsl + c * 2048);
        __syncthreads();

        const bool wave_active = (kb + 63 >= qw0 - (WIN_ - 1));
        if (wave_active) {
            f32x4 sacc[4] = {};
#pragma unroll
            for (int c4 = 0; c4 < 4; ++c4)
#pragma unroll
                for (int kblk = 0; kblk < 4; ++kblk) {
                    bf16x8 kf = *(const bf16x8*)&Ks[(kblk * 16 + l15) * 128 +
                                                    (((c4 * 4 + quad) ^ swz) * 8)];
                    sacc[kblk] =
                        __builtin_amdgcn_mfma_f32_16x16x32_bf16(kf, qf[c4], sacc[kblk], 0, 0, 0);
                }

            const int q = qw0 + l15;
            float sv[16];
            const bool interior = (kb + 63 <= qw0) && (kb >= qw0 + 15 - (WIN_ - 1));
            if (interior) {
#pragma unroll
                for (int kblk = 0; kblk < 4; ++kblk)
#pragma unroll
                    for (int r = 0; r < 4; ++r) sv[kblk * 4 + r] = sacc[kblk][r];
            } else {
#pragma unroll
                for (int kblk = 0; kblk < 4; ++kblk)
#pragma unroll
                    for (int r = 0; r < 4; ++r) {
                        const int key = kb + kblk * 16 + quad * 4 + r;
                        const bool valid = (key <= q) && (q - key < WIN_);
                        sv[kblk * 4 + r] = valid ? sacc[kblk][r] : -1e30f;
                    }
            }
            float mc = sv[0];
#pragma unroll
            for (int i = 1; i < 16; ++i) mc = fmaxf(mc, sv[i]);
            mc = fmaxf(mc, __shfl_xor(mc, 16, 64));
            mc = fmaxf(mc, __shfl_xor(mc, 32, 64));
            const float mnew = fmaxf(m, mc);
            const float al = __builtin_amdgcn_exp2f(m - mnew);
            float ls = 0.0f;
#pragma unroll
            for (int i = 0; i < 16; ++i) {
                sv[i] = __builtin_amdgcn_exp2f(sv[i] - mnew);
                ls += sv[i];
            }
            ls += __shfl_xor(ls, 16, 64);
            ls += __shfl_xor(ls, 32, 64);
            lsum = lsum * al + ls;
            m = mnew;
#pragma unroll
            for (int dblk = 0; dblk < 8; ++dblk) o[dblk] *= al;

            bf16* pw = &Ps[wave * 1024 + l15 * 64];
#pragma unroll
            for (int kblk = 0; kblk < 4; ++kblk) {
                bf16x4 pb = {(bf16)sv[kblk * 4 + 0], (bf16)sv[kblk * 4 + 1],
                             (bf16)sv[kblk * 4 + 2], (bf16)sv[kblk * 4 + 3]};
                const int phys = (kblk * 2 + (quad >> 1)) ^ swz;
                *(bf16x4*)&pw[phys * 8 + (quad & 1) * 4] = pb;
            }
#pragma unroll
            for (int kc = 0; kc < 2; ++kc) {
                const int up = ((kc * 4 + quad) ^ swz) * 8;
                bf16x8 pfv = *(const bf16x8*)&pw[up];
#pragma unroll
                for (int dblk = 0; dblk < 8; ++dblk) {
                    bf16x8 vf = *(const bf16x8*)&Vs[(dblk * 16 + l15) * 64 + up];
                    o[dblk] = __builtin_amdgcn_mfma_f32_16x16x32_bf16(vf, pfv, o[dblk], 0, 0, 0);
                }
            }
        }
        __syncthreads();
    }

    const float inv = 1.0f / lsum;
    const int q = qw0 + l15;
    bf16* ob = Out + (size_t)(b * S_ + q) * HD_ + h * 128;
#pragma unroll
    for (int dblk = 0; dblk < 8; ++dblk) {
        bf16x4 ov = {(bf16)(o[dblk][0] * inv), (bf16)(o[dblk][1] * inv),
                     (bf16)(o[dblk][2] * inv), (bf16)(o[dblk][3] * inv)};
        *(bf16x4*)&ob[dblk * 16 + quad * 4] = ov;
    }
}

// ---------------- launch ----------------
extern "C" void kernel_launch(void* const* d_in, const int* in_sizes, int n_in, void* d_out,
                              int out_size, void* d_ws, size_t ws_size, hipStream_t stream) {
    const float* x = (const float*)d_in[0];
    const float* cosp = (const float*)d_in[1];
    const float* sinp = (const float*)d_in[2];
    const float* Wq = (const float*)d_in[3];
    const float* Wk = (const float*)d_in[4];
    const float* Wv = (const float*)d_in[5];
    const float* Wo = (const float*)d_in[6];
    float* out = (float*)d_out;

    constexpr size_t MB = 1ull << 20;
    char* ws = (char*)d_ws;
    bf16* xb    = (bf16*)(ws + 0);          // x bf16 (4096x2048)        16 MB
    bf16* wqkv  = (bf16*)(ws + 16 * MB);    // Wq|Wk|Wv bf16 (3072x2048) 12 MB
    bf16* wo    = (bf16*)(ws + 28 * MB);    // Wo bf16 (2048x2048)        8 MB
    bf16* qn    = (bf16*)(ws + 40 * MB);    // (B,H,S,D)                 16 MB
    bf16* kn    = (bf16*)(ws + 56 * MB);    // (B,KV,S,D)                 4 MB
    bf16* vt    = (bf16*)(ws + 60 * MB);    // (B,KV,D,S)                 4 MB
    bf16* attnb = (bf16*)(ws + 64 * MB);    // (B,S,H*D)                 16 MB

    cvt_all<<<18432, 256, 0, stream>>>(x, Wq, Wk, Wv, Wo, xb);
    gemm_qkv8<<<dim3(16, 12), 512, 0, stream>>>(xb, wqkv, cosp, sinp, qn, kn, vt);
    attn_fwd<<<dim3(32, 16, 2), 256, 0, stream>>>(qn, kn, vt, attnb);
    gemm_bt8<<<dim3(16, 16), 512, 0, stream>>>(attnb, wo, out, 2048, 2048);
}

// Round 7
// 276.471 us; speedup vs baseline: 1.0674x; 1.0045x over previous
//
#include <hip/hip_runtime.h>
#include <stdint.h>

using bf16 = __bf16;
typedef __bf16 bf16x8 __attribute__((ext_vector_type(8)));
typedef __bf16 bf16x4 __attribute__((ext_vector_type(4)));
typedef float f32x4 __attribute__((ext_vector_type(4)));

#define H_ 16
#define KV_ 4
#define D_ 128
#define WIN_ 1024
#define B_ 2
#define S_ 2048
#define E_ 2048
#define HD_ 2048

// async global->LDS, 16B per lane. LDS dest must be wave-uniform base + lane*16.
__device__ __forceinline__ void gld_lds16(const void* gptr, void* lptr) {
    __builtin_amdgcn_global_load_lds(
        (__attribute__((address_space(1))) void*)(uintptr_t)gptr,
        (__attribute__((address_space(3))) void*)(uintptr_t)lptr, 16, 0, 0);
}

// ---------------- fused fp32 -> bf16 conversion (x, Wq, Wk, Wv, Wo -> one contiguous dst) ----
__global__ __launch_bounds__(256) void cvt_all(const float* __restrict__ x,
                                               const float* __restrict__ wq,
                                               const float* __restrict__ wk,
                                               const float* __restrict__ wv,
                                               const float* __restrict__ wo,
                                               bf16* __restrict__ dst) {
    int i = (blockIdx.x * 256 + threadIdx.x) * 4;  // into 18,874,368-elem concatenation
    const float* src;
    int off;
    if (i < 8388608)       { src = x;  off = 0; }
    else if (i < 12582912) { src = wq; off = 8388608; }
    else if (i < 13631488) { src = wk; off = 12582912; }
    else if (i < 14680064) { src = wv; off = 13631488; }
    else                   { src = wo; off = 14680064; }
    const float4 v = *(const float4*)(src + (i - off));
    bf16x4 o = {(bf16)v.x, (bf16)v.y, (bf16)v.z, (bf16)v.w};
    *(bf16x4*)(dst + i) = o;
}

#define SCHED0() __builtin_amdgcn_sched_barrier(0)
#define BAR()                          \
    do {                               \
        SCHED0();                      \
        __builtin_amdgcn_s_barrier();  \
        SCHED0();                      \
    } while (0)
#define WAITV(N) asm volatile("s_waitcnt vmcnt(" #N ")" ::: "memory")

// ===================== BK=32, 4-deep pipelined, register-double-buffered GEMM core ====
// LDS row = 32 bf16 = 64 B, 4 x 16B units/row. Bank-conflict swizzle (R7): phys unit p
// of row r holds logical unit p ^ ((r>>1)&3) -> within-quad accesses spread 2-way over
// bank groups (free), fixing R6's 4.87M conflicts. Staging thread t (row t>>2, phys
// t&3) pre-swizzles its SOURCE unit to (t&3)^((t>>3)&3); fragment reads use phys unit
// quad ^ ((l15>>1)&3) (row-dependent term is l15-uniform: rows differ by mult. of 32).
// Pipeline per tile u: stage(u+3) issue; MFMA tile u from REGISTERS; ds_read tile u+1
// frags (hidden under MFMA; buf valid since stage(u+1) retired at end of u-1);
// WAITV(4|3) counted (never 0 in steady state); one barrier per tile.

template <int NH>  // BN = NH*128; NH=2 -> 128KB LDS, NH=1 -> 96KB
__device__ __forceinline__ void gemm_core32(const bf16* __restrict__ A,
                                            const bf16* __restrict__ W, int m0,
                                            int n0, bf16* sm, f32x4 (&acc)[8][2 * NH]) {
    constexpr int K = 2048;  // both GEMMs have K=2048; 64 K-tiles of 32
    const int t = threadIdx.x;
    const int lane = t & 63;
    const int wave = t >> 6;
    const int l15 = lane & 15;
    const int quad = lane >> 4;
    const int fs2 = (l15 >> 1) & 3;          // read-side unit swizzle
    const int wm = (wave & 1) * 128;         // 2 M-waves x 128 rows
    const int wn = (wave >> 1) * (NH * 32);  // 4 N-waves x NH*32 cols

    bf16* const A0 = sm;                     // 4 A-buffers, 256x32 = 8192 elems each
    bf16* const A1 = sm + 8192;
    bf16* const A2 = sm + 16384;
    bf16* const A3 = sm + 24576;
    bf16* const B0 = sm + 32768;             // 4 B-buffers, NH*128 x 32 each
    bf16* const B1 = B0 + NH * 4096;
    bf16* const B2 = B0 + NH * 8192;
    bf16* const B3 = B0 + NH * 12288;

    // staging: thread t -> row (t>>2) [+128 for round 1], phys unit (t&3);
    // source unit pre-swizzled: (t&3)^((t>>3)&3)
    const bf16* Ap = A + (size_t)(m0 + (t >> 2)) * K + ((t & 3) ^ ((t >> 3) & 3)) * 8;
    const bf16* Wp = W + (size_t)(n0 + (t >> 2)) * K + ((t & 3) ^ ((t >> 3) & 3)) * 8;

    auto stA = [&](int u, bf16* d) {
        gld_lds16(Ap + u * 32, d + t * 8);
        gld_lds16(Ap + u * 32 + (size_t)128 * K, d + 4096 + t * 8);
    };
    auto stB = [&](int u, bf16* d) {
        gld_lds16(Wp + u * 32, d + t * 8);
        if constexpr (NH == 2) gld_lds16(Wp + u * 32 + (size_t)128 * K, d + 4096 + t * 8);
    };

    bf16x8 afX[8], afY[8], bfX[2 * NH], bfY[2 * NH];
    auto rdA = [&](const bf16* S, bf16x8 (&af)[8]) {
#pragma unroll
        for (int mi = 0; mi < 8; ++mi)
            af[mi] = *(const bf16x8*)&S[(wm + mi * 16 + l15) * 32 + (quad ^ fs2) * 8];
    };
    auto rdB = [&](const bf16* S, bf16x8 (&bf)[2 * NH]) {
#pragma unroll
        for (int j = 0; j < 2 * NH; ++j)
            bf[j] = *(const bf16x8*)&S[(wn + j * 16 + l15) * 32 + (quad ^ fs2) * 8];
    };
    auto MMA = [&](bf16x8 (&af)[8], bf16x8 (&bf)[2 * NH]) {
        __builtin_amdgcn_s_setprio(1);
#pragma unroll
        for (int mi = 0; mi < 8; ++mi)
#pragma unroll
            for (int j = 0; j < 2 * NH; ++j)
                acc[mi][j] = __builtin_amdgcn_mfma_f32_16x16x32_bf16(af[mi], bf[j],
                                                                     acc[mi][j], 0, 0, 0);
        __builtin_amdgcn_s_setprio(0);
    };

#define GT(U, AFM, BFM, AFR, BFR, RA, RB, SA, SB, DOST, WMODE)                      \
    do {                                                                            \
        if (DOST) { stA((U) + 3, SA); stB((U) + 3, SB); }                           \
        MMA(AFM, BFM);                                                              \
        rdA(RA, AFR);                                                               \
        rdB(RB, BFR);                                                               \
        SCHED0();                                                                   \
        if ((WMODE) == 1) {                                                         \
            if constexpr (NH == 2) { WAITV(4); } else { WAITV(3); }                 \
        } else if ((WMODE) == 0) {                                                  \
            WAITV(0);                                                               \
        }                                                                           \
        BAR();                                                                      \
    } while (0)

    // prologue: stage tiles 0,1,2; retire 0 and 1 (2 stays in flight); read frag 0.
    stA(0, A0); stB(0, B0);
    stA(1, A1); stB(1, B1);
    stA(2, A2); stB(2, B2);
    SCHED0();
    if constexpr (NH == 2) { WAITV(4); } else { WAITV(3); }
    BAR();
    rdA(A0, afX);
    rdB(B0, bfX);

    // tiles 0..59: 15 iterations x 4 (buffer cycle and X/Y parity both period-4)
    for (int it = 0; it < 15; ++it) {
        const int u = it * 4;
        GT(u + 0, afX, bfX, afY, bfY, A1, B1, A3, B3, 1, 1);
        GT(u + 1, afY, bfY, afX, bfX, A2, B2, A0, B0, 1, 1);
        GT(u + 2, afX, bfX, afY, bfY, A3, B3, A1, B1, 1, 1);
        GT(u + 3, afY, bfY, afX, bfX, A0, B0, A2, B2, 1, 1);
    }
    GT(60, afX, bfX, afY, bfY, A1, B1, A3, B3, 1, 1);   // stages tile 63 -> b3
    GT(61, afY, bfY, afX, bfX, A2, B2, A0, B0, 0, 0);   // drain: stage(63) retired
    GT(62, afX, bfX, afY, bfY, A3, B3, A1, B1, 0, -1);  // reads frag 63 from b3
    MMA(afY, bfY);                                      // tile 63
#undef GT
}

// ---------------- QKV GEMM (256x256 tiles) with fused RoPE + RMSNorm + V-transpose ----
__global__ __launch_bounds__(512, 2) void gemm_qkv8(const bf16* __restrict__ A,
                                                    const bf16* __restrict__ W,
                                                    const float* __restrict__ cosp,
                                                    const float* __restrict__ sinp,
                                                    bf16* __restrict__ qn,
                                                    bf16* __restrict__ kn,
                                                    bf16* __restrict__ vt) {
    __shared__ alignas(16) bf16 sm[65536];  // 128 KB (K-loop); epilogue chunk aliases it
    const int flat = blockIdx.y * 16 + blockIdx.x;  // nwg=192, 192%8==0 -> bijective
    const int swz = (flat & 7) * 24 + (flat >> 3);  // XCD-contiguous tile chunks
    const int m0 = (swz & 15) * 256;
    const int n0 = (swz >> 4) * 256;

    f32x4 acc[8][4] = {};
    gemm_core32<2>(A, W, m0, n0, sm, acc);

    const int t = threadIdx.x;
    const int lane = t & 63;
    const int wave = t >> 6;
    const int l15 = lane & 15;
    const int quad = lane >> 4;
    const int wm = (wave & 1) * 128;
    const int wn = (wave >> 1) * 64;
    bf16* Cs = sm;  // [128][264] per chunk; 264*2B row stride = 33x16B (aligned, 4-way max)

#pragma unroll
    for (int ch = 0; ch < 2; ++ch) {
        __syncthreads();
        if (wm == ch * 128) {  // half the waves own this 128-row chunk
#pragma unroll
            for (int mi = 0; mi < 8; ++mi) {
                const int rl = mi * 16 + quad * 4;
#pragma unroll
                for (int nf = 0; nf < 4; ++nf) {
                    const int col = wn + nf * 16 + l15;
#pragma unroll
                    for (int r = 0; r < 4; ++r)
                        Cs[(rl + r) * 264 + col] = (bf16)acc[mi][nf][r];
                }
            }
        }
        __syncthreads();

        if (n0 < 2560) {
            // q/k tile: 2 threads per (token-row, head); each handles d = half*32..+31
            const int rt = t >> 1;       // 0..255
            const int row = rt & 127;
            const int hh = rt >> 7;      // which of the 2 heads in this tile
            const int half = t & 1;
            const int gr = m0 + ch * 128 + row;
            const int bb = gr >> 11;
            const int s = gr & 2047;
            const int unit = (n0 >> 7) + hh;
            const bf16* crow = &Cs[row * 264 + hh * 128 + half * 32];
            const float* cp = cosp + s * 64 + half * 32;
            const float* sp = sinp + s * 64 + half * 32;
            bf16x8 xa[4], xb2[4];
#pragma unroll
            for (int u = 0; u < 4; ++u) {
                xa[u] = *(const bf16x8*)(crow + u * 8);
                xb2[u] = *(const bf16x8*)(crow + 64 + u * 8);
            }
            float y1[32], y2[32], ss = 0.0f;
#pragma unroll
            for (int u = 0; u < 4; ++u)
#pragma unroll
                for (int e = 0; e < 8; ++e) {
                    const int jj = u * 8 + e;
                    const float x1 = (float)xa[u][e];
                    const float x2 = (float)xb2[u][e];
                    const float c = cp[jj];
                    const float sn = sp[jj];
                    y1[jj] = x1 * c + x2 * sn;
                    y2[jj] = x2 * c - x1 * sn;
                    ss += y1[jj] * y1[jj] + y2[jj] * y2[jj];
                }
            ss += __shfl_xor(ss, 1, 64);
            float rr = rsqrtf(ss * (1.0f / 128.0f) + 1.1920929e-7f);
            bf16* dst;
            if (unit < 16) {
                rr *= 0.12751740f;  // D^-0.5 * log2(e): exp2-domain softmax in attn
                dst = qn + ((size_t)(bb * H_ + unit) * S_ + s) * 128 + half * 32;
            } else {
                dst = kn + ((size_t)(bb * KV_ + (unit - 16)) * S_ + s) * 128 + half * 32;
            }
#pragma unroll
            for (int u = 0; u < 4; ++u) {
                bf16x8 p1, p2;
#pragma unroll
                for (int e = 0; e < 8; ++e) {
                    p1[e] = (bf16)(y1[u * 8 + e] * rr);
                    p2[e] = (bf16)(y2[u * 8 + e] * rr);
                }
                *(bf16x8*)(dst + u * 8) = p1;
                *(bf16x8*)(dst + 64 + u * 8) = p2;
            }
        } else {
            // V tile: transpose chunk -> vt[(b,jv,d,s)]; thread owns one (head,d), 64 s
            const int hh = t >> 8;
            const int d = (t >> 1) & 127;
            const int sl0 = (t & 1) * 64;
            const int jv = (n0 >> 7) + hh - 20;
            const int base = m0 + ch * 128;
            const int bb = base >> 11;
            const int sW = (base & 2047) + sl0;
            bf16* vdst = vt + ((size_t)(bb * KV_ + jv) * 128 + d) * S_ + sW;
#pragma unroll
            for (int u = 0; u < 8; ++u) {
                bf16x8 pk;
#pragma unroll
                for (int e = 0; e < 8; ++e)
                    pk[e] = Cs[(sl0 + u * 8 + e) * 264 + hh * 128 + d];
                *(bf16x8*)(vdst + u * 8) = pk;
            }
        }
    }
}

// ---------------- out-projection: C[m,n] = sum_k A[m,k] * W[n,k], 256x128 tiles -------
__global__ __launch_bounds__(512, 2) void gemm_bt8(const bf16* __restrict__ A,
                                                   const bf16* __restrict__ W,
                                                   float* __restrict__ C, int K,
                                                   int ldc) {
    __shared__ alignas(16) bf16 sm[49152];  // 96 KB
    const int flat = blockIdx.y * 16 + blockIdx.x;  // nwg=256
    const int swz = (flat & 7) * 32 + (flat >> 3);
    const int m0 = (swz & 15) * 256;
    const int n0 = (swz >> 4) * 128;

    f32x4 acc[8][2] = {};
    gemm_core32<1>(A, W, m0, n0, sm, acc);

    const int t = threadIdx.x;
    const int lane = t & 63;
    const int l15 = lane & 15;
    const int quad = lane >> 4;
    const int wave = t >> 6;
    const int wm = (wave & 1) * 128;
    const int wn = (wave >> 1) * 32;
#pragma unroll
    for (int mi = 0; mi < 8; ++mi) {
        const int row = m0 + wm + mi * 16 + quad * 4;
#pragma unroll
        for (int j = 0; j < 2; ++j) {
            const int col = n0 + wn + j * 16 + l15;
#pragma unroll
            for (int r = 0; r < 4; ++r) C[(size_t)(row + r) * ldc + col] = acc[mi][j][r];
        }
    }
}

// ---------------- flash attention, sliding window, S^T orientation --------------------
// R7: 512 threads / 8 waves; each staged K/V tile is shared by TWO q-heads of the same
// GQA group (waves 0-3 -> head 2y, waves 4-7 -> head 2y+1; both have hk = y>>... = y/1).
// Per-wave compute identical to the proven R4 kernel. Staging bytes and barrier count
// per MFMA halve; waves/CU unchanged at 16 (2 blocks x 8 waves, LDS 48 KB).
__global__ __launch_bounds__(512, 4) void attn_fwd(const bf16* __restrict__ Qn,
                                                   const bf16* __restrict__ Kn,
                                                   const bf16* __restrict__ Vt,
                                                   bf16* __restrict__ Out) {
    __shared__ alignas(16) bf16 Ks[64 * 128];   // 16 KB, [64 s][128 d], unit^=(row&7)
    __shared__ alignas(16) bf16 Vs[128 * 64];   // 16 KB, [128 d][64 s], unit^=(row&7)
    __shared__ alignas(16) bf16 Ps[8 * 16 * 64];// 16 KB

    const int t = threadIdx.x;
    const int lane = t & 63;
    const int wave = t >> 6;           // 0..7
    const int l15 = lane & 15;
    const int quad = lane >> 4;
    const int swz = l15 & 7;
    const int qb0 = blockIdx.x * 64;
    const int h = blockIdx.y * 2 + (wave >> 2);   // two heads per block, same hk
    const int b = blockIdx.z;
    const int hk = blockIdx.y >> 1;               // block-uniform (h=2y,2y+1 share it)
    const int qw0 = qb0 + (wave & 3) * 16;

    const bf16* qbase = Qn + ((size_t)((b * H_ + h) * S_) + qw0 + l15) * 128;
    bf16x8 qf[4];
#pragma unroll
    for (int c4 = 0; c4 < 4; ++c4) qf[c4] = *(const bf16x8*)(qbase + c4 * 32 + quad * 8);

    f32x4 o[8] = {};
    float m = -1e30f, lsum = 0.0f;

    const bf16* kroot = Kn + (size_t)((b * KV_ + hk) * S_) * 128;
    const bf16* vroot = Vt + (size_t)((b * KV_ + hk) * 128) * S_;

    // staging: 8 waves x 2 chunks of 1024 B each for K and V.
    // K chunk m covers s-rows 4m..4m+3: lane l -> row 4m+(l>>4), phys unit l&15,
    //   src unit (l&15)^(row&7). V chunk m covers d-rows 8m..8m+7: lane l ->
    //   row 8m+(l>>3), phys unit l&7, src unit (l&7)^(row&7).
    auto stage = [&](int kb) {
#pragma unroll
        for (int c = 0; c < 2; ++c) {
            const int mchunk = wave * 2 + c;
            const int kr = 4 * mchunk + (lane >> 4);
            gld_lds16(kroot + (size_t)(kb + kr) * 128 + ((lane & 15) ^ (kr & 7)) * 8,
                      &Ks[mchunk * 512 + lane * 8]);
            const int vr = 8 * mchunk + (lane >> 3);
            gld_lds16(vroot + (size_t)vr * S_ + kb + ((lane & 7) ^ (vr & 7)) * 8,
                      &Vs[mchunk * 512 + lane * 8]);
        }
    };

    int lo = qb0 - (WIN_ - 1);
    if (lo < 0) lo = 0;
    const int kb_start = lo & ~63;
    const int kb_end = qb0 + 64;

    for (int kb = kb_start; kb < kb_end; kb += 64) {
        stage(kb);
        __syncthreads();

        const bool wave_active = (kb + 63 >= qw0 - (WIN_ - 1));
        if (wave_active) {
            f32x4 sacc[4] = {};
            __builtin_amdgcn_s_setprio(1);
#pragma unroll
            for (int c4 = 0; c4 < 4; ++c4)
#pragma unroll
                for (int kblk = 0; kblk < 4; ++kblk) {
                    bf16x8 kf = *(const bf16x8*)&Ks[(kblk * 16 + l15) * 128 +
                                                    (((c4 * 4 + quad) ^ swz) * 8)];
                    sacc[kblk] =
                        __builtin_amdgcn_mfma_f32_16x16x32_bf16(kf, qf[c4], sacc[kblk], 0, 0, 0);
                }
            __builtin_amdgcn_s_setprio(0);

            const int q = qw0 + l15;
            float sv[16];
            const bool interior = (kb + 63 <= qw0) && (kb >= qw0 + 15 - (WIN_ - 1));
            if (interior) {
#pragma unroll
                for (int kblk = 0; kblk < 4; ++kblk)
#pragma unroll
                    for (int r = 0; r < 4; ++r) sv[kblk * 4 + r] = sacc[kblk][r];
            } else {
#pragma unroll
                for (int kblk = 0; kblk < 4; ++kblk)
#pragma unroll
                    for (int r = 0; r < 4; ++r) {
                        const int key = kb + kblk * 16 + quad * 4 + r;
                        const bool valid = (key <= q) && (q - key < WIN_);
                        sv[kblk * 4 + r] = valid ? sacc[kblk][r] : -1e30f;
                    }
            }
            float mc = sv[0];
#pragma unroll
            for (int i = 1; i < 16; ++i) mc = fmaxf(mc, sv[i]);
            mc = fmaxf(mc, __shfl_xor(mc, 16, 64));
            mc = fmaxf(mc, __shfl_xor(mc, 32, 64));
            const float mnew = fmaxf(m, mc);
            const float al = __builtin_amdgcn_exp2f(m - mnew);
            float ls = 0.0f;
#pragma unroll
            for (int i = 0; i < 16; ++i) {
                sv[i] = __builtin_amdgcn_exp2f(sv[i] - mnew);
                ls += sv[i];
            }
            ls += __shfl_xor(ls, 16, 64);
            ls += __shfl_xor(ls, 32, 64);
            lsum = lsum * al + ls;
            m = mnew;
#pragma unroll
            for (int dblk = 0; dblk < 8; ++dblk) o[dblk] *= al;

            bf16* pw = &Ps[wave * 1024 + l15 * 64];
#pragma unroll
            for (int kblk = 0; kblk < 4; ++kblk) {
                bf16x4 pb = {(bf16)sv[kblk * 4 + 0], (bf16)sv[kblk * 4 + 1],
                             (bf16)sv[kblk * 4 + 2], (bf16)sv[kblk * 4 + 3]};
                const int phys = (kblk * 2 + (quad >> 1)) ^ swz;
                *(bf16x4*)&pw[phys * 8 + (quad & 1) * 4] = pb;
            }
            __builtin_amdgcn_s_setprio(1);
#pragma unroll
            for (int kc = 0; kc < 2; ++kc) {
                const int up = ((kc * 4 + quad) ^ swz) * 8;
                bf16x8 pfv = *(const bf16x8*)&pw[up];
#pragma unroll
                for (int dblk = 0; dblk < 8; ++dblk) {
                    bf16x8 vf = *(const bf16x8*)&Vs[(dblk * 16 + l15) * 64 + up];
                    o[dblk] = __builtin_amdgcn_mfma_f32_16x16x32_bf16(vf, pfv, o[dblk], 0, 0, 0);
                }
            }
            __builtin_amdgcn_s_setprio(0);
        }
        __syncthreads();
    }

    const float inv = 1.0f / lsum;
    const int q = qw0 + l15;
    bf16* ob = Out + (size_t)(b * S_ + q) * HD_ + h * 128;
#pragma unroll
    for (int dblk = 0; dblk < 8; ++dblk) {
        bf16x4 ov = {(bf16)(o[dblk][0] * inv), (bf16)(o[dblk][1] * inv),
                     (bf16)(o[dblk][2] * inv), (bf16)(o[dblk][3] * inv)};
        *(bf16x4*)&ob[dblk * 16 + quad * 4] = ov;
    }
}

// ---------------- launch ----------------
extern "C" void kernel_launch(void* const* d_in, const int* in_sizes, int n_in, void* d_out,
                              int out_size, void* d_ws, size_t ws_size, hipStream_t stream) {
    const float* x = (const float*)d_in[0];
    const float* cosp = (const float*)d_in[1];
    const float* sinp = (const float*)d_in[2];
    const float* Wq = (const float*)d_in[3];
    const float* Wk = (const float*)d_in[4];
    const float* Wv = (const float*)d_in[5];
    const float* Wo = (const float*)d_in[6];
    float* out = (float*)d_out;

    constexpr size_t MB = 1ull << 20;
    char* ws = (char*)d_ws;
    bf16* xb    = (bf16*)(ws + 0);          // x bf16 (4096x2048)        16 MB
    bf16* wqkv  = (bf16*)(ws + 16 * MB);    // Wq|Wk|Wv bf16 (3072x2048) 12 MB
    bf16* wo    = (bf16*)(ws + 28 * MB);    // Wo bf16 (2048x2048)        8 MB
    bf16* qn    = (bf16*)(ws + 40 * MB);    // (B,H,S,D)                 16 MB
    bf16* kn    = (bf16*)(ws + 56 * MB);    // (B,KV,S,D)                 4 MB
    bf16* vt    = (bf16*)(ws + 60 * MB);    // (B,KV,D,S)                 4 MB
    bf16* attnb = (bf16*)(ws + 64 * MB);    // (B,S,H*D)                 16 MB

    cvt_all<<<18432, 256, 0, stream>>>(x, Wq, Wk, Wv, Wo, xb);
    gemm_qkv8<<<dim3(16, 12), 512, 0, stream>>>(xb, wqkv, cosp, sinp, qn, kn, vt);
    attn_fwd<<<dim3(32, 8, 2), 512, 0, stream>>>(qn, kn, vt, attnb);
    gemm_bt8<<<dim3(16, 16), 512, 0, stream>>>(attnb, wo, out, 2048, 2048);
}